// Round 1
// baseline (1617.305 us; speedup 1.0000x reference)
//
#include <hip/hip_runtime.h>

// EncoderGRUODE: B=256, T=512, D_IN=64, H=128
// R3: latency attack. R2 was 47% VALUBusy at 2 waves/SIMD (8 waves/CU) with 6
// barriers/step -> ~53% SIMD idle. Changes:
//  - 1024 thr/block (16 waves/CU, 4/SIMD): same per-CU work, 2x latency hiding.
//  - 5 barriers/step: output matvec merged into next step's k1 phase (pairs two
//    independent dot chains per phase); input-gate dots merged into k3 phase.
//  - W_ih staged in LDS (pad 17 float4/row) so regs fit the 128-VGPR cap at
//    4 waves/SIMD (W_node+W_hh+W_out stay pinned in VGPRs).
// Predicted: Occupancy 23->46%, VALUBusy 47->~70%, dur 1227 -> ~800us.

#define NB      256
#define TB      1024
#define TSTEP   512
#define DIN     64
#define HD      128
#define WIH_PAD 17   // float4 stride per W_ih row (16 data + 1 pad)

typedef float v2f __attribute__((ext_vector_type(2)));

__device__ __forceinline__ float fast_tanh(float v) {
    float e = __expf(2.0f * v);
    return 1.0f - 2.0f / (e + 1.0f);
}
__device__ __forceinline__ float fast_sigmoid(float v) {
    return 1.0f / (1.0f + __expf(-v));
}

// 8-lane butterfly: DPP xor1, xor2 (quad) + ds_swizzle xor4. All 8 lanes get sum.
__device__ __forceinline__ float red8(float v) {
    v += __int_as_float(__builtin_amdgcn_update_dpp(
            0, __float_as_int(v), 0xB1, 0xF, 0xF, true)); // xor 1
    v += __int_as_float(__builtin_amdgcn_update_dpp(
            0, __float_as_int(v), 0x4E, 0xF, 0xF, true)); // xor 2
    v += __int_as_float(__builtin_amdgcn_ds_swizzle(__float_as_int(v), 0x101F)); // xor 4
    return v;
}
__device__ __forceinline__ float red16(float v) {
    v = red8(v);
    v += __int_as_float(__builtin_amdgcn_ds_swizzle(__float_as_int(v), 0x201F)); // xor 8
    return v;
}

__global__ __launch_bounds__(TB, 4) void gruode_kernel(
    const float* __restrict__ x,         // [B, T, DIN]
    const float* __restrict__ tp,        // [B, T] (row 0 used)
    const int*   __restrict__ samp_mask, // [T]
    const float* __restrict__ W_ih,      // [3H, DIN]
    const float* __restrict__ W_hh,      // [3H, H]
    const float* __restrict__ b_ih,      // [3H]
    const float* __restrict__ b_hh,      // [3H]
    const float* __restrict__ W_node,    // [H, H]
    const float* __restrict__ b_node,    // [H]
    const float* __restrict__ W_out,     // [DIN, H]
    const float* __restrict__ b_out,     // [DIN]
    float*       __restrict__ out)       // [B*T, DIN]
{
    const int t   = threadIdx.x;
    const int b   = blockIdx.x;
    const int j   = t >> 3;        // hidden row owned by this 8-lane group
    const int ks  = t & 7;         // k-slice within row group
    const int j64 = t >> 4;        // output row owned by this 16-lane group
    const int ko  = t & 15;        // k-slice within out group

    __shared__ __align__(16) float sh_h [HD];
    __shared__ __align__(16) float sh_t0[HD];
    __shared__ __align__(16) float sh_t1[HD];
    __shared__ __align__(16) float sh_in[DIN];
    __shared__ __align__(16) float sh_po[DIN];
    __shared__ float4 sWih[3 * HD * WIH_PAD];   // ~102 KB, padded vs bank alias

    const float4* Wn4  = (const float4*)W_node;  // [128][32 f4]
    const float4* Whh4 = (const float4*)W_hh;    // [384][32 f4]
    const float4* Wih4 = (const float4*)W_ih;    // [384][16 f4]
    const float4* Wo4  = (const float4*)W_out;   // [64][32 f4]

    // ---- stage W_ih -> LDS (padded row stride) ----
    for (int idx = t; idx < 3 * HD * 16; idx += TB) {
        int row = idx >> 4, col = idx & 15;
        sWih[row * WIH_PAD + col] = Wih4[idx];
    }

    // ---- W_node, W_hh, W_out -> registers (72 VGPRs of weights) ----
    v2f Wn[8], Whr[8], Whz[8], Whn[8];
    #pragma unroll
    for (int i = 0; i < 4; ++i) {
        float4 w;
        w = Wn4 [j*32 + i*8 + ks];          Wn [2*i] = (v2f){w.x, w.y}; Wn [2*i+1] = (v2f){w.z, w.w};
        w = Whh4[(0*HD + j)*32 + i*8 + ks]; Whr[2*i] = (v2f){w.x, w.y}; Whr[2*i+1] = (v2f){w.z, w.w};
        w = Whh4[(1*HD + j)*32 + i*8 + ks]; Whz[2*i] = (v2f){w.x, w.y}; Whz[2*i+1] = (v2f){w.z, w.w};
        w = Whh4[(2*HD + j)*32 + i*8 + ks]; Whn[2*i] = (v2f){w.x, w.y}; Whn[2*i+1] = (v2f){w.z, w.w};
    }
    v2f Wo[4];
    #pragma unroll
    for (int i = 0; i < 2; ++i) {
        float4 w = Wo4[j64*32 + i*16 + ko];
        Wo[2*i] = (v2f){w.x, w.y}; Wo[2*i+1] = (v2f){w.z, w.w};
    }
    // Pin: opaque to rematerialization.
    #pragma unroll
    for (int i = 0; i < 8; ++i) {
        asm volatile("" : "+v"(Wn[i]));  asm volatile("" : "+v"(Whr[i]));
        asm volatile("" : "+v"(Whz[i])); asm volatile("" : "+v"(Whn[i]));
    }
    #pragma unroll
    for (int i = 0; i < 4; ++i) { asm volatile("" : "+v"(Wo[i])); }

    const float bn   = b_node[j];
    const float br   = b_ih[0*HD + j] + b_hh[0*HD + j];
    const float bz   = b_ih[1*HD + j] + b_hh[1*HD + j];
    const float bi_n = b_ih[2*HD + j];
    const float bh_n = b_hh[2*HD + j];
    const float bo   = b_out[j64];

    if (t < HD) sh_h[t] = 0.0f;

    // stream state
    float tp_cur  = tp[0];
    float tp_prev = tp_cur - 0.01f;          // dts[0] = 0.01
    int   m_cur   = samp_mask[0];
    const float* xbase = x   + (size_t)b * TSTEP * DIN;
    float*       obase = out + (size_t)b * TSTEP * DIN;
    float xr = (t < DIN) ? xbase[t] : 0.0f;

    __syncthreads();

    const float4* h4  = (const float4*)sh_h;
    const float4* t04 = (const float4*)sh_t0;
    const float4* t14 = (const float4*)sh_t1;
    const float4* in4 = (const float4*)sh_in;

    // 1/8-sliced packed dot over a 128-float LDS vector (broadcast reads)
    auto hdot = [&](const v2f (&w)[8], const float4* buf) -> float {
        v2f a0 = {0.f, 0.f}, a1 = {0.f, 0.f};
        #pragma unroll
        for (int i = 0; i < 4; ++i) {
            float4 v = buf[i*8 + ks];
            a0 += w[2*i]   * (v2f){v.x, v.y};
            a1 += w[2*i+1] * (v2f){v.z, v.w};
        }
        v2f a = a0 + a1;
        return a.x + a.y;
    };

    float hj = 0.0f;   // h carried in registers (all 8 group lanes hold row j)

    #pragma unroll 1
    for (int s = 0; s < TSTEP; ++s) {
        const float dt = tp_cur - tp_prev;

        // ---- P1: k1 dot + output matvec of previous h_new (both read sh_h) --
        float k1 = fast_tanh(red8(hdot(Wn, h4)) + bn);
        {
            v2f ao = {0.f, 0.f};
            #pragma unroll
            for (int i = 0; i < 2; ++i) {
                float4 v = h4[i*16 + ko];
                ao += Wo[2*i]   * (v2f){v.x, v.y};
                ao += Wo[2*i+1] * (v2f){v.z, v.w};
            }
            float o = red16(ao.x + ao.y) + bo;   // = h_new(s-1)@Wo^T + bo
            if (ko == 0) {
                sh_po[j64] = o;                  // prev_out for this step's input
                if (s > 0) obase[(size_t)(s-1) * DIN + j64] = o;
            }
        }
        if (ks == 0) sh_t0[j] = fmaf(0.5f * dt, k1, hj);
        __syncthreads();                                   // B1

        // ---- P2: k2 dot; build input vec; prefetch next-step stream ----
        if (t < DIN) sh_in[t] = m_cur ? xr : sh_po[t];
        float k2 = fast_tanh(red8(hdot(Wn, t04)) + bn);
        if (ks == 0) sh_t1[j] = fmaf(0.5f * dt, k2, hj);
        {
            const int sn = (s + 1 < TSTEP) ? s + 1 : s;
            tp_prev = tp_cur;
            tp_cur  = tp[sn];
            m_cur   = samp_mask[sn];
            if (t < DIN) xr = xbase[(size_t)sn * DIN + t];
        }
        __syncthreads();                                   // B2

        // ---- P3: k3 dot + input-gate dots (read sh_in, weights from LDS) ----
        float k3 = fast_tanh(red8(hdot(Wn, t14)) + bn);
        float crs, czs, cns;
        {
            v2f cr = {0.f,0.f}, cz = {0.f,0.f}, cn = {0.f,0.f};
            #pragma unroll
            for (int i = 0; i < 2; ++i) {
                float4 v = in4[i*8 + ks];
                v2f lo = {v.x, v.y}, hi = {v.z, v.w};
                float4 wr = sWih[(0*HD + j)*WIH_PAD + i*8 + ks];
                float4 wz = sWih[(1*HD + j)*WIH_PAD + i*8 + ks];
                float4 wn = sWih[(2*HD + j)*WIH_PAD + i*8 + ks];
                cr += (v2f){wr.x, wr.y} * lo; cr += (v2f){wr.z, wr.w} * hi;
                cz += (v2f){wz.x, wz.y} * lo; cz += (v2f){wz.z, wz.w} * hi;
                cn += (v2f){wn.x, wn.y} * lo; cn += (v2f){wn.z, wn.w} * hi;
            }
            crs = red8(cr.x + cr.y);
            czs = red8(cz.x + cz.y);
            cns = red8(cn.x + cn.y);
        }
        if (ks == 0) sh_t0[j] = fmaf(dt, k3, hj);
        __syncthreads();                                   // B3

        // ---- P4: k4 dot; h_ode ----
        float k4 = fast_tanh(red8(hdot(Wn, t04)) + bn);
        float hode = fmaf(dt * (1.0f / 6.0f),
                          (k1 + 2.0f * k2) + (2.0f * k3 + k4), hj);
        if (ks == 0) sh_t1[j] = hode;                      // t1 = h_ode vector
        __syncthreads();                                   // B4

        // ---- P5: GRU hidden-gate dots + combine ----
        v2f ar = {0.f,0.f}, az = {0.f,0.f}, an = {0.f,0.f};
        #pragma unroll
        for (int i = 0; i < 4; ++i) {
            float4 v = t14[i*8 + ks];
            v2f lo = {v.x, v.y}, hi = {v.z, v.w};
            ar += Whr[2*i] * lo; ar += Whr[2*i+1] * hi;
            az += Whz[2*i] * lo; az += Whz[2*i+1] * hi;
            an += Whn[2*i] * lo; an += Whn[2*i+1] * hi;
        }
        float rr  = fast_sigmoid(red8(ar.x + ar.y) + crs + br);
        float zz  = fast_sigmoid(red8(az.x + az.y) + czs + bz);
        float hnv = red8(an.x + an.y) + bh_n;
        float inv = cns + bi_n;
        float nn  = fast_tanh(fmaf(rr, hnv, inv));
        float hnew = fmaf(zz, hode - nn, nn);              // (1-z)n + z*h_ode
        hj = hnew;
        if (ks == 0) sh_h[j] = hnew;
        __syncthreads();                                   // B5
    }

    // ---- epilogue: out[T-1] = h_new(T-1) @ W_out^T + b_out ----
    {
        v2f ao = {0.f, 0.f};
        #pragma unroll
        for (int i = 0; i < 2; ++i) {
            float4 v = h4[i*16 + ko];
            ao += Wo[2*i]   * (v2f){v.x, v.y};
            ao += Wo[2*i+1] * (v2f){v.z, v.w};
        }
        float o = red16(ao.x + ao.y) + bo;
        if (ko == 0) obase[(size_t)(TSTEP - 1) * DIN + j64] = o;
    }
}

extern "C" void kernel_launch(void* const* d_in, const int* in_sizes, int n_in,
                              void* d_out, int out_size, void* d_ws, size_t ws_size,
                              hipStream_t stream) {
    (void)in_sizes; (void)n_in; (void)d_ws; (void)ws_size; (void)out_size;
    const float* x      = (const float*)d_in[0];
    const float* tp     = (const float*)d_in[1];
    const int*   mask   = (const int*)  d_in[2];
    const float* W_ih   = (const float*)d_in[3];
    const float* W_hh   = (const float*)d_in[4];
    const float* b_ih   = (const float*)d_in[5];
    const float* b_hh   = (const float*)d_in[6];
    const float* W_node = (const float*)d_in[7];
    const float* b_node = (const float*)d_in[8];
    const float* W_out  = (const float*)d_in[9];
    const float* b_out  = (const float*)d_in[10];
    float* outp = (float*)d_out;

    gruode_kernel<<<NB, TB, 0, stream>>>(x, tp, mask, W_ih, W_hh, b_ih, b_hh,
                                         W_node, b_node, W_out, b_out, outp);
}